// Round 12
// baseline (28.468 us; speedup 1.0000x reference)
//
#include <hip/hip_runtime.h>
#include <hip/hip_fp16.h>

#define MROWS 512
#define NCOLS 8192
#define NVALS 4096
#define BLOCK 512
#define NW 8
#define EPSF 1e-10f

typedef unsigned int u32;
typedef unsigned long long u64;
typedef unsigned short u16;

#define TOTMASK ((1ull << 44) - 1ull)
#define FXSCALE 16777216.0f   // 2^24

// transposed layout: thread t owns logical e=8t..8t+7 at phys (i<<9)+t (conflict-free)
__device__ __forceinline__ int TP(int e) { return ((e & 7) << 9) | (e >> 3); }
__device__ __forceinline__ u16 f2h(float x) { return __half_as_ushort(__float2half_rn(x)); }
__device__ __forceinline__ float h2f(u16 h) { return __half2float(__ushort_as_half(h)); }
// packed (count=1)<<44 | fixed-point exp(pred): deterministic function of pred16
__device__ __forceinline__ u64 packCE(u16 ph) {
    const float e = __expf(h2f(ph));
    return (1ull << 44) | (u64)(e * FXSCALE + 0.5f);
}

__global__ __launch_bounds__(BLOCK, 2) void listmle_row_kernel(
    const float* __restrict__ outputs,
    const float* __restrict__ runtime,
    const int*   __restrict__ idxs,
    float* __restrict__ row_out)
{
    // 32 + 32 KB + scratch = 64.3 KB -> 2 blocks/CU (grid caps residency at 2 anyway)
    __shared__ u64 B[NVALS];   // dedup-min (j13|rt24|pred16) -> entries (rt24|j13|exph16) @ TP(pos)
    __shared__ u64 D[NVALS];   // packed (cnt<<44 | tot*2^24) per bucket (TP layout)
                               // after scan: two u32[4096]: bases/cursors/ends + S_excl f32
    __shared__ u64 s_sc[NW];
    __shared__ float s_ps[NW];
    __shared__ double s_lg[NW];

    u32* Cc = reinterpret_cast<u32*>(D);           // bucket base -> cursor -> end (TP index)
    u32* Sf = reinterpret_cast<u32*>(D) + NVALS;   // S_excl f32 bits (TP index)

    const int tid = threadIdx.x, lane = tid & 63, wave = tid >> 6;
    const int row = blockIdx.x;
    const float* rp = outputs + (size_t)row * NCOLS;
    const float* rr = runtime + (size_t)row * NCOLS;
    const int*   ri = idxs    + (size_t)row * NCOLS;

    // ---- P0: load 16 items/thread; pack pk = (j<<40)|(rt24<<16)|pred_f16; init B, D ----
    u64 pk[16]; u32 pidx[8];
    #pragma unroll
    for (int q = 0; q < 4; ++q) {
        const int b0 = (q << 11) + (tid << 2);
        const int4   i4 = *reinterpret_cast<const int4*>(ri + b0);
        const float4 r4 = *reinterpret_cast<const float4*>(rr + b0);
        const float4 p4 = *reinterpret_cast<const float4*>(rp + b0);
        pidx[q*2]   = ((u32)i4.x & 0xFFFFu) | ((u32)i4.y << 16);
        pidx[q*2+1] = ((u32)i4.z & 0xFFFFu) | ((u32)i4.w << 16);
        const float rv[4] = { r4.x, r4.y, r4.z, r4.w };
        const float pv[4] = { p4.x, p4.y, p4.z, p4.w };
        #pragma unroll
        for (int r = 0; r < 4; ++r) {
            u32 u = (u32)(rv[r] * 16777216.0f);          // exact monotone 24-bit key
            u = u > 0xFFFFFFu ? 0xFFFFFFu : u;
            const u32 j = (u32)b0 + (u32)r;
            pk[q*4+r] = ((u64)j << 40) | ((u64)u << 16) | (u64)f2h(pv[r]);
        }
    }
    #pragma unroll
    for (int i = 0; i < 8; ++i) { B[(i<<9)+tid] = ~0ull; D[(i<<9)+tid] = 0ull; }
    __syncthreads();                                    // B1

    // ---- P1: FUSED dedup + bucket count/total via compensated packed atomics.
    //     atomicMin linearizes per value-slot: every installed pk is added once and
    //     subtracted once by its displacer (recomputed bit-identically from pred16),
    //     so after the barrier D holds exact winner counts+totals (integer ring). ----
    #pragma unroll
    for (int m = 0; m < 16; ++m) {
        const u32 v = (pidx[m>>1] >> ((m & 1) << 4)) & 0xFFFFu;
        const u64 mine = pk[m];
        const u64 old = atomicMin(&B[TP((int)v)], mine);
        if (mine < old) {
            atomicAdd(&D[TP((int)((mine >> 28) & 0xFFFu))], packCE((u16)(mine & 0xFFFFu)));
            if (old != ~0ull)
                atomicAdd(&D[TP((int)((old >> 28) & 0xFFFu))],
                          0ull - packCE((u16)(old & 0xFFFFu)));
        }
    }
    __syncthreads();                                    // B2

    // ---- P2: value-owner extracts 8 winners (cf b64); psum; read D + u64 scan ----
    u64 own[8]; float e8[8];
    u32 keptmask = 0;
    float psum = 0.f;
    #pragma unroll
    for (int i = 0; i < 8; ++i) {
        const u64 x = B[(i<<9)+tid];                    // = B[TP(8*tid+i)]
        own[i] = x;
        if (x != ~0ull) {
            keptmask |= 1u << i;
            const float pd = h2f((u16)(x & 0xFFFFu));
            psum += pd;
            e8[i] = __expf(pd);
        }
    }
    #pragma unroll
    for (int off = 32; off > 0; off >>= 1) psum += __shfl_down(psum, off);
    if (lane == 0) s_ps[wave] = psum;

    u64 d8[8], lsum = 0ull;
    #pragma unroll
    for (int i = 0; i < 8; ++i) { d8[i] = D[(i<<9)+tid]; lsum += d8[i]; }
    u64 xsu = lsum;
    #pragma unroll
    for (int off = 1; off < 64; off <<= 1) { const u64 y = __shfl_up(xsu, off); if (lane >= off) xsu += y; }
    if (lane == 63) s_sc[wave] = xsu;
    __syncthreads();                                    // B3 (all D reads complete)

    u64 runp = xsu - lsum;
    #pragma unroll
    for (int w = 0; w < NW; ++w) if (w < wave) runp += s_sc[w];
    #pragma unroll
    for (int i = 0; i < 8; ++i) {
        Cc[(i<<9)+tid] = (u32)(runp >> 44);                                    // bucket base
        Sf[(i<<9)+tid] = __float_as_uint((float)(runp & TOTMASK) * (1.0f / FXSCALE)); // S_excl
        runp += d8[i];
    }
    __syncthreads();                                    // B4 (bases + S live)

    // ---- P3: scatter entries (rt24|j13|exph16) by atomic arrival; cursor IS base array ----
    #pragma unroll
    for (int i = 0; i < 8; ++i) {
        if (keptmask & (1u << i)) {
            const u64 x = own[i];
            const u32 rt24 = (u32)((x >> 16) & 0xFFFFFFu);
            const u32 j    = (u32)((x >> 40) & 0x1FFFu);
            const u32 pos  = atomicAdd(&Cc[TP((int)(rt24 >> 12))], 1u);
            B[TP((int)pos)] = ((u64)rt24 << 29) | ((u64)j << 16) | (u64)f2h(e8[i]);
        }
    }
    __syncthreads();                                    // B5 (entries in B; Cc[b] = end of b)

    // ---- P4: per-entry within-bucket inclusive prefix + log ----
    double logacc = 0.0;
    #pragma unroll
    for (int i = 0; i < 8; ++i) {
        const u64 x = B[(i<<9)+tid];                    // = B[TP(8*tid+i)]
        if (own[i] != ~0ull || x != ~0ull) { /* keep lanes converged-ish; real guard below */ }
        const u32 p = (u32)(8 * tid + i);
        if (p < (u32)NVALS) {
            // only positions < K hold entries; detect via sentinel: unscattered slots
            // retain dedup-min residue only if overwritten... guard by K via Cc? cheaper:
        }
        (void)x;
    }
    // NOTE: replaced by exact K-guard below
    {
        // recover K = total count from last bucket end
        const u32 K = Cc[TP(NVALS - 1)];
        logacc = 0.0;
        #pragma unroll
        for (int i = 0; i < 8; ++i) {
            const u32 p = (u32)(8 * tid + i);
            if (p < K) {
                const u64 x = B[(i<<9)+tid];            // = B[TP(p)]
                const u64 ku = x >> 16;                 // 37-bit unique key (rt24|j13)
                const int b  = (int)(x >> 41);
                const u32 start = b ? Cc[TP(b - 1)] : 0u;
                const u32 end   = Cc[TP(b)];
                double dsm = 0.0;
                for (u32 q = start; q < end; ++q) {
                    const u64 y = B[TP((int)q)];
                    if ((y >> 16) <= ku) dsm += (double)h2f((u16)(y & 0xFFFFu));
                }
                const float S = __uint_as_float(Sf[TP(b)]);
                logacc += (double)__logf(S + (float)dsm + EPSF);
            }
        }
    }
    #pragma unroll
    for (int off = 32; off > 0; off >>= 1) logacc += __shfl_down(logacc, off);
    if (lane == 0) s_lg[wave] = logacc;
    __syncthreads();                                    // B6

    if (tid == 0) {
        double lt = 0.0; float pt = 0.f;
        #pragma unroll
        for (int w = 0; w < NW; ++w) { lt += s_lg[w]; pt += s_ps[w]; }
        row_out[row] = (float)(lt - (double)pt);        // K*mx cancels exactly
    }
}

__global__ __launch_bounds__(256) void listmle_finalize(
    const float* __restrict__ row_out, float* __restrict__ out)
{
    __shared__ double red_d[4];
    const int tid = threadIdx.x;
    const int lane = tid & 63, wave = tid >> 6;
    double acc = 0.0;
    for (int r = tid; r < MROWS; r += 256) acc += (double)row_out[r];
    #pragma unroll
    for (int off = 32; off > 0; off >>= 1) acc += __shfl_down(acc, off);
    if (lane == 0) red_d[wave] = acc;
    __syncthreads();
    if (tid == 0) {
        double tot = 0.0;
        for (int w = 0; w < 4; ++w) tot += red_d[w];
        out[0] = (float)(tot / (double)MROWS);
    }
}

extern "C" void kernel_launch(void* const* d_in, const int* in_sizes, int n_in,
                              void* d_out, int out_size, void* d_ws, size_t ws_size,
                              hipStream_t stream) {
    const float* outputs = (const float*)d_in[0];
    const float* runtime = (const float*)d_in[1];
    const int*   idxs    = (const int*)d_in[2];
    float* out = (float*)d_out;
    float* ws  = (float*)d_ws;

    listmle_row_kernel<<<MROWS, BLOCK, 0, stream>>>(outputs, runtime, idxs, ws);
    listmle_finalize<<<1, 256, 0, stream>>>(ws, out);
}

// Round 13
// 26.432 us; speedup vs baseline: 1.0770x; 1.0770x over previous
//
#include <hip/hip_runtime.h>
#include <hip/hip_fp16.h>

#define MROWS 512
#define NCOLS 8192
#define NVALS 4096
#define NB    8192
#define BLOCK 512
#define NW 8
#define EPSF 1e-10f

typedef unsigned int u32;
typedef unsigned long long u64;
typedef unsigned short u16;

#define TOTMASK ((1ull << 44) - 1ull)
#define FXS 16384.0f            // 2^14 fixed-point scale for exp totals

// transposed layouts (conflict-free 8- or 16-per-thread chunks)
__device__ __forceinline__ int TP(int e)  { return ((e & 7)  << 9) | (e >> 3); }  // 4096
__device__ __forceinline__ int TPB(int e) { return ((e & 15) << 9) | (e >> 4); }  // 8192
__device__ __forceinline__ u16 f2h(float x) { return __half_as_ushort(__float2half_rn(x)); }
__device__ __forceinline__ float h2f(u16 h) { return __half2float(__ushort_as_half(h)); }

__global__ __launch_bounds__(BLOCK, 2) void listmle_row_kernel(
    const float* __restrict__ outputs,
    const float* __restrict__ runtime,
    const int*   __restrict__ idxs,
    float* __restrict__ row_out)
{
    // 32 (B) + 32 (D) KB + scratch = 64.3 KB -> 2 blocks/CU (grid caps at 2 anyway)
    __shared__ u64 B[NVALS];   // dedup-min (j13|rt24|pred16) -> entries (rt24|j13|exph16) @ TP(pos)
    __shared__ u32 D[NB];      // per-bucket (cnt<<24 | tot*2^14) -> (base<<16 | bf16(S_excl)) (TPB)
    __shared__ u64 s_sc[NW];
    __shared__ float s_ps[NW];
    __shared__ double s_lg[NW];

    const int tid = threadIdx.x, lane = tid & 63, wave = tid >> 6;
    const int row = blockIdx.x;
    const float* rp = outputs + (size_t)row * NCOLS;
    const float* rr = runtime + (size_t)row * NCOLS;
    const int*   ri = idxs    + (size_t)row * NCOLS;

    // ---- P0: load 16 items/thread; pack pk = (j<<40)|(rt24<<16)|pred_f16; init B, D ----
    u64 pk[16]; u32 pidx[8];
    #pragma unroll
    for (int q = 0; q < 4; ++q) {
        const int b0 = (q << 11) + (tid << 2);
        const int4   i4 = *reinterpret_cast<const int4*>(ri + b0);
        const float4 r4 = *reinterpret_cast<const float4*>(rr + b0);
        const float4 p4 = *reinterpret_cast<const float4*>(rp + b0);
        pidx[q*2]   = ((u32)i4.x & 0xFFFFu) | ((u32)i4.y << 16);
        pidx[q*2+1] = ((u32)i4.z & 0xFFFFu) | ((u32)i4.w << 16);
        const float rv[4] = { r4.x, r4.y, r4.z, r4.w };
        const float pv[4] = { p4.x, p4.y, p4.z, p4.w };
        #pragma unroll
        for (int r = 0; r < 4; ++r) {
            u32 u = (u32)(rv[r] * 16777216.0f);          // exact monotone 24-bit key
            u = u > 0xFFFFFFu ? 0xFFFFFFu : u;
            const u32 j = (u32)b0 + (u32)r;
            pk[q*4+r] = ((u64)j << 40) | ((u64)u << 16) | (u64)f2h(pv[r]);
        }
    }
    #pragma unroll
    for (int i = 0; i < 8; ++i) B[(i<<9)+tid] = ~0ull;
    #pragma unroll
    for (int i = 0; i < 16; ++i) D[(i<<9)+tid] = 0u;
    __syncthreads();                                    // B1

    // ---- P1: dedup + payload in ONE pass: min over j carries (rt24, pred16) ----
    #pragma unroll
    for (int m = 0; m < 16; ++m) {
        const u32 v = (pidx[m>>1] >> ((m & 1) << 4)) & 0xFFFFu;
        atomicMin(&B[TP((int)v)], pk[m]);
    }
    __syncthreads();                                    // B2

    // ---- P2: value-owner extracts 8 winners (cf b64); psum; packed u32 count+total
    //          per bucket (integer atomics: exact + commutative -> deterministic) ----
    u64 own[8]; float e8[8];
    u32 keptmask = 0;
    float psum = 0.f;
    #pragma unroll
    for (int i = 0; i < 8; ++i) {
        const u64 x = B[(i<<9)+tid];                    // = B[TP(8*tid+i)]
        own[i] = x;
        if (x != ~0ull) {
            keptmask |= 1u << i;
            const float pd = h2f((u16)(x & 0xFFFFu));
            psum += pd;
            const float e = __expf(pd);                 // no mx: exp(pred) <= ~70
            e8[i] = e;
            const int b = (int)((x >> 27) & 0x1FFFu);   // rt24 >> 11
            atomicAdd(&D[TPB(b)], (1u << 24) | (u32)(e * FXS + 0.5f));
        }
    }
    #pragma unroll
    for (int off = 32; off > 0; off >>= 1) psum += __shfl_down(psum, off);
    if (lane == 0) s_ps[wave] = psum;

    // widened u64 scan of 8192 packed u32 (16/thread, TPB layout)
    u64 d16[16], lsum = 0ull;
    #pragma unroll
    for (int i = 0; i < 16; ++i) {
        const u32 d = D[(i<<9)+tid];
        d16[i] = ((u64)(d >> 24) << 44) | (u64)(d & 0xFFFFFFu);
        lsum += d16[i];
    }
    u64 xsu = lsum;
    #pragma unroll
    for (int off = 1; off < 64; off <<= 1) { const u64 y = __shfl_up(xsu, off); if (lane >= off) xsu += y; }
    if (lane == 63) s_sc[wave] = xsu;
    __syncthreads();                                    // B3 (all D reads complete)

    u64 runp = xsu - lsum, grand = 0ull;
    #pragma unroll
    for (int w = 0; w < NW; ++w) { const u64 t = s_sc[w]; if (w < wave) runp += t; grand += t; }
    const u32 K = (u32)(grand >> 44);
    #pragma unroll
    for (int i = 0; i < 16; ++i) {
        const u32 base = (u32)(runp >> 44);
        const float S = (float)(runp & TOTMASK) * (1.0f / FXS);
        const u32 sb = __float_as_uint(S);
        const u32 s16 = (sb + 0x7FFFu + ((sb >> 16) & 1u)) >> 16;   // bf16 RN
        D[(i<<9)+tid] = (base << 16) | s16;
        runp += d16[i];
    }
    __syncthreads();                                    // B4 (packed base|S live)

    // ---- P3: scatter entries (rt24|j13|exph16) by atomic arrival on packed cursor ----
    #pragma unroll
    for (int i = 0; i < 8; ++i) {
        if (keptmask & (1u << i)) {
            const u64 x = own[i];
            const u32 rt24 = (u32)((x >> 16) & 0xFFFFFFu);
            const u32 j    = (u32)((x >> 40) & 0x1FFFu);
            const u32 pos  = atomicAdd(&D[TPB((int)(rt24 >> 11))], 1u << 16) >> 16;
            B[TP((int)pos)] = ((u64)rt24 << 29) | ((u64)j << 16) | (u64)f2h(e8[i]);
        }
    }
    __syncthreads();                                    // B5 (entries in B; D[b]>>16 = end of b)

    // ---- P4: per-entry within-bucket inclusive prefix + log ----
    double logacc = 0.0;
    #pragma unroll
    for (int i = 0; i < 8; ++i) {
        const u32 p = (u32)(8 * tid + i);
        if (p < K) {
            const u64 x = B[(i<<9)+tid];                // = B[TP(p)]
            const u64 ku = x >> 16;                     // 37-bit unique key (rt24|j13)
            const int b  = (int)(x >> 40);              // 13-bit bucket
            const u32 dcur = D[TPB(b)];
            const u32 start = b ? (D[TPB(b - 1)] >> 16) : 0u;
            const u32 end   = dcur >> 16;
            const float S   = __uint_as_float((dcur & 0xFFFFu) << 16);
            double dsm = 0.0;
            for (u32 q = start; q < end; ++q) {
                const u64 y = B[TP((int)q)];
                if ((y >> 16) <= ku) dsm += (double)h2f((u16)(y & 0xFFFFu));
            }
            logacc += (double)__logf(S + (float)dsm + EPSF);
        }
    }
    #pragma unroll
    for (int off = 32; off > 0; off >>= 1) logacc += __shfl_down(logacc, off);
    if (lane == 0) s_lg[wave] = logacc;
    __syncthreads();                                    // B6

    if (tid == 0) {
        double lt = 0.0; float pt = 0.f;
        #pragma unroll
        for (int w = 0; w < NW; ++w) { lt += s_lg[w]; pt += s_ps[w]; }
        row_out[row] = (float)(lt - (double)pt);        // K*mx cancels algebraically
    }
}

__global__ __launch_bounds__(64) void listmle_finalize(
    const float* __restrict__ row_out, float* __restrict__ out)
{
    const int lane = threadIdx.x;
    double acc = 0.0;
    #pragma unroll
    for (int i = 0; i < 8; ++i) acc += (double)row_out[lane + (i << 6)];
    #pragma unroll
    for (int off = 32; off > 0; off >>= 1) acc += __shfl_down(acc, off);
    if (lane == 0) out[0] = (float)(acc / (double)MROWS);
}

extern "C" void kernel_launch(void* const* d_in, const int* in_sizes, int n_in,
                              void* d_out, int out_size, void* d_ws, size_t ws_size,
                              hipStream_t stream) {
    const float* outputs = (const float*)d_in[0];
    const float* runtime = (const float*)d_in[1];
    const int*   idxs    = (const int*)d_in[2];
    float* out = (float*)d_out;
    float* ws  = (float*)d_ws;

    listmle_row_kernel<<<MROWS, BLOCK, 0, stream>>>(outputs, runtime, idxs, ws);
    listmle_finalize<<<1, 64, 0, stream>>>(ws, out);
}